// Round 1
// baseline (153.940 us; speedup 1.0000x reference)
//
#include <hip/hip_runtime.h>
#include <float.h>

#define Bb 2
#define Ll 256
#define Ss 384
#define Hh 768
#define Tc 16
#define Dc 50
#define WD 100
#define OUTC 968   // H + WD + 2*Dc

// ---------------- ws init + global min of bert_emb (encoded uint atomicMin) ----------------

__global__ void init_ws(unsigned* wmin) {
    if (blockIdx.x == 0 && threadIdx.x == 0) *wmin = 0xFFFFFFFFu;
}

__device__ inline unsigned enc_f32(float f) {
    unsigned k = __float_as_uint(f);
    return (k & 0x80000000u) ? ~k : (k | 0x80000000u);
}
__device__ inline float dec_f32(unsigned k) {
    unsigned bits = (k & 0x80000000u) ? (k ^ 0x80000000u) : ~k;
    return __uint_as_float(bits);
}

__global__ void min_reduce(const float* __restrict__ x, int n, unsigned* wmin) {
    int i = blockIdx.x * blockDim.x + threadIdx.x;
    float m = FLT_MAX;
    for (; i < n; i += gridDim.x * blockDim.x) m = fminf(m, x[i]);
    #pragma unroll
    for (int off = 32; off; off >>= 1) m = fminf(m, __shfl_down(m, off, 64));
    if ((threadIdx.x & 63) == 0) atomicMin(wmin, enc_f32(m));
}

// ---------------- word_reps partial max (S split into 4 chunks) ----------------
// grid: 3 (h-chunk) * 32 (l-tile) * 8 (b*chunk) = 768 blocks, 256 threads

#define NCHUNK 4
#define SCHUNK (Ss / NCHUNK)   // 96
#define LT 8

__global__ __launch_bounds__(256) void word_reps_partial(
        const float* __restrict__ bert, const int* __restrict__ p2w,
        float* __restrict__ partial) {
    int blk = blockIdx.x;
    int hc = blk % 3;
    int lt = (blk / 3) % 32;
    int bc = blk / (3 * 32);     // 0..7  -> b*4 + chunk
    int b  = bc >> 2;
    int ch = bc & 3;
    int h  = hc * 256 + threadIdx.x;
    int l0 = lt * LT;

    float acc[LT];
    #pragma unroll
    for (int i = 0; i < LT; i++) acc[i] = -FLT_MAX;

    const float* bb = bert + ((size_t)b * Ss) * Hh + h;
    const int*   pm = p2w + ((size_t)b * Ll + l0) * Ss;
    int s0 = ch * SCHUNK;
    for (int s = s0; s < s0 + SCHUNK; s++) {
        float v = bb[(size_t)s * Hh];
        #pragma unroll
        for (int i = 0; i < LT; i++) {
            int m = pm[i * Ss + s];                  // wave-uniform (scalar) load
            acc[i] = fmaxf(acc[i], m ? v : -FLT_MAX);
        }
    }
    #pragma unroll
    for (int i = 0; i < LT; i++)
        partial[(((size_t)ch * Bb + b) * Ll + (l0 + i)) * Hh + h] = acc[i];
}

// ---------------- char bi-LSTM, one block per (chain n, direction) ----------------

__device__ inline float tanh_fast(float x) {
    float e = __expf(2.f * x);
    return 1.f - 2.f / (e + 1.f);
}
__device__ inline float sigmoid_fast(float x) {
    return 1.f / (1.f + __expf(-x));
}

__global__ __launch_bounds__(256) void lstm_kernel(
        const int* __restrict__ char_ids, const int* __restrict__ char_count,
        const float* __restrict__ char_table,
        const float* __restrict__ Wih_f, const float* __restrict__ Whh_f,
        const float* __restrict__ bih_f, const float* __restrict__ bhh_f,
        const float* __restrict__ Wih_b, const float* __restrict__ Whh_b,
        const float* __restrict__ bih_b, const float* __restrict__ bhh_b,
        float* __restrict__ out) {
    int n   = blockIdx.x;   // 0..511 == b*L + l
    int dir = blockIdx.y;   // 0 fwd, 1 bwd
    const float* Wih = dir ? Wih_b : Wih_f;
    const float* Whh = dir ? Whh_b : Whh_f;
    const float* bih = dir ? bih_b : bih_f;
    const float* bhh = dir ? bhh_b : bhh_f;
    int tid = threadIdx.x;

    __shared__ __align__(16) float xs[Tc][52];
    __shared__ float xp[Tc][200];
    __shared__ float gs[200];
    __shared__ __align__(16) float hs[52];

    int len = char_count[n];
    if (len < 1) len = 1;

    // stage x (with backward time reversal of the valid prefix)
    for (int e = tid; e < Tc * 52; e += 256) {
        int t = e / 52, d = e - t * 52;
        int st = dir ? (t < len ? len - 1 - t : t) : t;
        float v = 0.f;
        if (d < Dc) v = char_table[char_ids[n * Tc + st] * Dc + d];
        xs[t][d] = v;
    }
    if (tid < 52) hs[tid] = 0.f;
    __syncthreads();

    float w[52];
    float bias = 0.f;
    if (tid < 200) {
        #pragma unroll
        for (int j = 0; j < Dc; j++) w[j] = Wih[tid * Dc + j];
        w[50] = 0.f; w[51] = 0.f;
        bias = bih[tid] + bhh[tid];
        // x projection for all timesteps (gate preactivation minus the h part)
        for (int t = 0; t < Tc; t++) {
            float a = bias;
            #pragma unroll
            for (int j = 0; j < 52; j += 4) {
                float4 xv = *(const float4*)&xs[t][j];
                a += xv.x * w[j] + xv.y * w[j+1] + xv.z * w[j+2] + xv.w * w[j+3];
            }
            xp[t][tid] = a;
        }
        // swap weight registers to the recurrent matrix
        #pragma unroll
        for (int j = 0; j < Dc; j++) w[j] = Whh[tid * Dc + j];
    }
    __syncthreads();

    float c = 0.f, maxv = -FLT_MAX;
    for (int t = 0; t < Tc; t++) {
        if (tid < 200) {
            float g = xp[t][tid];
            #pragma unroll
            for (int j = 0; j < 52; j += 4) {
                float4 hv = *(const float4*)&hs[j];
                g += hv.x * w[j] + hv.y * w[j+1] + hv.z * w[j+2] + hv.w * w[j+3];
            }
            gs[tid] = g;
        }
        __syncthreads();
        if (tid < Dc) {
            float si = sigmoid_fast(gs[tid]);
            float sf = sigmoid_fast(gs[tid + 50]);
            float tg = tanh_fast(gs[tid + 100]);
            float so = sigmoid_fast(gs[tid + 150]);
            c = sf * c + si * tg;
            float h = so * tanh_fast(c);
            hs[tid] = h;
            if (t < len) maxv = fmaxf(maxv, h);   // ragged max; valid region == scan steps < len for both dirs
        }
        __syncthreads();
    }
    if (tid < Dc)
        out[(size_t)n * OUTC + (Hh + WD) + dir * Dc + tid] = maxv;
}

// ---------------- finalize: reduce word_reps partials + word-embedding gather ----------------

__global__ __launch_bounds__(256) void finalize(
        const float* __restrict__ partial, const unsigned* __restrict__ wmin,
        const int* __restrict__ word_ids, const float* __restrict__ word_table,
        float* __restrict__ out) {
    int idx = blockIdx.x * blockDim.x + threadIdx.x;
    if (idx >= Bb * Ll * OUTC) return;
    int col = idx % OUTC;
    int bl  = idx / OUTC;
    if (col < Hh) {
        float m = -FLT_MAX;
        #pragma unroll
        for (int ch = 0; ch < NCHUNK; ch++)
            m = fmaxf(m, partial[((size_t)ch * Bb * Ll + bl) * Hh + col]);
        if (m == -FLT_MAX) m = dec_f32(*wmin);   // fully-masked row -> global min fill
        out[idx] = m;
    } else if (col < Hh + WD) {
        out[idx] = word_table[(size_t)word_ids[bl] * WD + (col - Hh)];
    }
    // col >= H+WD written by lstm_kernel
}

extern "C" void kernel_launch(void* const* d_in, const int* in_sizes, int n_in,
                              void* d_out, int out_size, void* d_ws, size_t ws_size,
                              hipStream_t stream) {
    const float* bert       = (const float*)d_in[0];
    const int*   p2w        = (const int*)d_in[1];
    const int*   word_ids   = (const int*)d_in[2];
    const int*   char_count = (const int*)d_in[3];
    const int*   char_ids   = (const int*)d_in[4];
    // d_in[5] token_masks_char: consistent with char_count, unused
    const float* word_table = (const float*)d_in[6];
    const float* char_table = (const float*)d_in[7];
    const float* Wih_f = (const float*)d_in[8];
    const float* Whh_f = (const float*)d_in[9];
    const float* bih_f = (const float*)d_in[10];
    const float* bhh_f = (const float*)d_in[11];
    const float* Wih_b = (const float*)d_in[12];
    const float* Whh_b = (const float*)d_in[13];
    const float* bih_b = (const float*)d_in[14];
    const float* bhh_b = (const float*)d_in[15];
    float* out = (float*)d_out;

    unsigned* wmin  = (unsigned*)d_ws;
    float* partial  = (float*)((char*)d_ws + 256);   // NCHUNK*B*L*H floats = 6.3 MB

    init_ws<<<1, 64, 0, stream>>>(wmin);
    min_reduce<<<256, 256, 0, stream>>>(bert, Bb * Ss * Hh, wmin);
    word_reps_partial<<<768, 256, 0, stream>>>(bert, p2w, partial);
    lstm_kernel<<<dim3(512, 2), 256, 0, stream>>>(
        char_ids, char_count, char_table,
        Wih_f, Whh_f, bih_f, bhh_f, Wih_b, Whh_b, bih_b, bhh_b, out);
    finalize<<<(Bb * Ll * OUTC + 255) / 256, 256, 0, stream>>>(
        partial, wmin, word_ids, word_table, out);
}

// Round 2
// 151.396 us; speedup vs baseline: 1.0168x; 1.0168x over previous
//
#include <hip/hip_runtime.h>
#include <float.h>

#define Bb 2
#define Ll 256
#define Ss 384
#define Hh 768
#define Tc 16
#define Dc 50
#define WD 100
#define CV 128
#define NG 200     // 4*Dc gates
#define OUTC 968   // H + WD + 2*Dc

// ws layout (floats):
//   [0, 256)    minv partials (one per prep block)
//   [256, ...)  xproj table: [2 dirs][128 cids][200 gates], bias folded in

__device__ inline float tanh_fast(float x) {
    float e = __expf(2.f * x);
    return 1.f - 2.f / (e + 1.f);
}
__device__ inline float sigmoid_fast(float x) {
    return 1.f / (1.f + __expf(-x));
}

// ---------------- prep: min partials | xproj table | word-embed gather ----------------
// grid 576: [0,256) min partials, [256,512) xproj (dir*128+cid), [512,576) gather

__global__ __launch_bounds__(256) void prep_kernel(
        const float* __restrict__ bert, const float* __restrict__ char_table,
        const float* __restrict__ Wih_f, const float* __restrict__ bih_f, const float* __restrict__ bhh_f,
        const float* __restrict__ Wih_b, const float* __restrict__ bih_b, const float* __restrict__ bhh_b,
        const int* __restrict__ word_ids, const float* __restrict__ word_table,
        float* __restrict__ minp, float* __restrict__ xpt, float* __restrict__ out) {
    int blk = blockIdx.x, tid = threadIdx.x;
    if (blk < 256) {
        const int n = Bb * Ss * Hh;
        float m = FLT_MAX;
        for (int i = blk * 256 + tid; i < n; i += 256 * 256) m = fminf(m, bert[i]);
        #pragma unroll
        for (int off = 32; off; off >>= 1) m = fminf(m, __shfl_down(m, off, 64));
        __shared__ float red[4];
        if ((tid & 63) == 0) red[tid >> 6] = m;
        __syncthreads();
        if (tid == 0) minp[blk] = fminf(fminf(red[0], red[1]), fminf(red[2], red[3]));
    } else if (blk < 512) {
        int idx = blk - 256;            // dir*128 + cid
        int dir = idx >> 7, cid = idx & 127;
        const float* Wih = dir ? Wih_b : Wih_f;
        const float* bih = dir ? bih_b : bih_f;
        const float* bhh = dir ? bhh_b : bhh_f;
        __shared__ float ct[Dc];
        if (tid < Dc) ct[tid] = char_table[cid * Dc + tid];
        __syncthreads();
        if (tid < NG) {
            float a = bih[tid] + bhh[tid];
            #pragma unroll
            for (int j = 0; j < Dc; j++) a += Wih[tid * Dc + j] * ct[j];
            xpt[idx * NG + tid] = a;
        }
    } else {
        for (int i = (blk - 512) * 256 + tid; i < Bb * Ll * WD; i += 64 * 256) {
            int bl = i / WD, d = i - bl * WD;
            out[(size_t)bl * OUTC + Hh + d] = word_table[(size_t)word_ids[bl] * WD + d];
        }
    }
}

// ---------------- word_reps masked max, direct to out ----------------
// grid 384 = 3 h-chunks * 64 l-tiles * 2 b; LT=4 rows per block

__global__ __launch_bounds__(256) void word_kernel(
        const float* __restrict__ bert, const int* __restrict__ p2w,
        const float* __restrict__ minp, float* __restrict__ out) {
    int tid = threadIdx.x;
    __shared__ float sminv;
    if (tid < 64) {
        float m = fminf(fminf(minp[tid], minp[tid + 64]),
                        fminf(minp[tid + 128], minp[tid + 192]));
        #pragma unroll
        for (int off = 32; off; off >>= 1) m = fminf(m, __shfl_down(m, off, 64));
        if (tid == 0) sminv = m;
    }
    __syncthreads();
    int blk = blockIdx.x;
    int hc = blk % 3;
    int lt = (blk / 3) & 63;
    int b  = blk / 192;
    int h  = hc * 256 + tid;
    int l0 = lt * 4;

    float acc[4];
    #pragma unroll
    for (int i = 0; i < 4; i++) acc[i] = -FLT_MAX;

    const float* bb = bert + (size_t)b * Ss * Hh + h;
    const int*   pm = p2w + ((size_t)b * Ll + l0) * Ss;
    for (int s = 0; s < Ss; s++) {
        float v = bb[(size_t)s * Hh];
        #pragma unroll
        for (int i = 0; i < 4; i++) {
            int m = pm[i * Ss + s];              // wave-uniform -> scalar load
            acc[i] = fmaxf(acc[i], m ? v : -FLT_MAX);
        }
    }
    float mv = sminv;
    #pragma unroll
    for (int i = 0; i < 4; i++) {
        float a = (acc[i] == -FLT_MAX) ? mv : acc[i];   // fully-masked row -> global min
        out[((size_t)(b * Ll + l0 + i)) * OUTC + h] = a;
    }
}

// ---------------- char bi-LSTM: one block per (chain, dir), xproj from table ----------------

__global__ __launch_bounds__(256) void lstm_kernel(
        const int* __restrict__ char_ids, const int* __restrict__ char_count,
        const float* __restrict__ Whh_f, const float* __restrict__ Whh_b,
        const float* __restrict__ xpt, float* __restrict__ out) {
    int n = blockIdx.x, dir = blockIdx.y, tid = threadIdx.x;
    const float* Whh = dir ? Whh_b : Whh_f;

    __shared__ float xg[Tc][NG];
    __shared__ float gs[NG];
    __shared__ __align__(16) float hs[52];
    __shared__ int scid[Tc];

    int len = char_count[n];
    if (len < 1) len = 1;
    if (tid < Tc) {
        int t = tid;
        int st = dir ? (t < len ? len - 1 - t : t) : t;   // bwd: reverse valid prefix
        scid[t] = char_ids[n * Tc + st];
    }
    if (tid < 52) hs[tid] = 0.f;
    __syncthreads();

    for (int e = tid; e < Tc * NG; e += 256) {
        int t = e / NG, g = e - t * NG;
        xg[t][g] = xpt[(dir * CV + scid[t]) * NG + g];    // coalesced row gather
    }
    float w[52];
    if (tid < NG) {
        #pragma unroll
        for (int j = 0; j < Dc; j++) w[j] = Whh[tid * Dc + j];
        w[50] = 0.f; w[51] = 0.f;
    }
    __syncthreads();

    float c = 0.f, maxv = -FLT_MAX;
    for (int t = 0; t < Tc; t++) {
        if (tid < NG) {
            float g = xg[t][tid];
            #pragma unroll
            for (int j = 0; j < 52; j += 4) {
                float4 hv = *(const float4*)&hs[j];      // broadcast reads
                g += hv.x * w[j] + hv.y * w[j+1] + hv.z * w[j+2] + hv.w * w[j+3];
            }
            gs[tid] = g;
        }
        __syncthreads();
        if (tid < Dc) {
            float si = sigmoid_fast(gs[tid]);
            float sf = sigmoid_fast(gs[tid + 50]);
            float tg = tanh_fast(gs[tid + 100]);
            float so = sigmoid_fast(gs[tid + 150]);
            c = sf * c + si * tg;
            float h = so * tanh_fast(c);
            hs[tid] = h;
            if (t < len) maxv = fmaxf(maxv, h);          // ragged max (scan order == valid region both dirs)
        }
        __syncthreads();
    }
    if (tid < Dc)
        out[(size_t)n * OUTC + (Hh + WD) + dir * Dc + tid] = maxv;
}

extern "C" void kernel_launch(void* const* d_in, const int* in_sizes, int n_in,
                              void* d_out, int out_size, void* d_ws, size_t ws_size,
                              hipStream_t stream) {
    const float* bert       = (const float*)d_in[0];
    const int*   p2w        = (const int*)d_in[1];
    const int*   word_ids   = (const int*)d_in[2];
    const int*   char_count = (const int*)d_in[3];
    const int*   char_ids   = (const int*)d_in[4];
    // d_in[5] token_masks_char: consistent with char_count, unused
    const float* word_table = (const float*)d_in[6];
    const float* char_table = (const float*)d_in[7];
    const float* Wih_f = (const float*)d_in[8];
    const float* Whh_f = (const float*)d_in[9];
    const float* bih_f = (const float*)d_in[10];
    const float* bhh_f = (const float*)d_in[11];
    const float* Wih_b = (const float*)d_in[12];
    const float* Whh_b = (const float*)d_in[13];
    const float* bih_b = (const float*)d_in[14];
    const float* bhh_b = (const float*)d_in[15];
    float* out = (float*)d_out;

    float* minp = (float*)d_ws;          // 256 floats
    float* xpt  = minp + 256;            // 2*128*200 floats (~205 KB)

    prep_kernel<<<576, 256, 0, stream>>>(
        bert, char_table, Wih_f, bih_f, bhh_f, Wih_b, bih_b, bhh_b,
        word_ids, word_table, minp, xpt, out);
    word_kernel<<<384, 256, 0, stream>>>(bert, p2w, minp, out);
    lstm_kernel<<<dim3(512, 2), 256, 0, stream>>>(
        char_ids, char_count, Whh_f, Whh_b, xpt, out);
}

// Round 3
// 146.852 us; speedup vs baseline: 1.0483x; 1.0309x over previous
//
#include <hip/hip_runtime.h>
#include <float.h>

#define Bb 2
#define Ll 256
#define Ss 384
#define Hh 768
#define Tc 16
#define Dc 50
#define WD 100
#define CV 128
#define NG 200     // 4*Dc gates
#define OUTC 968   // H + WD + 2*Dc

// ws layout (floats):
//   [0, 256)    minv partials (one per prep min-block)
//   [256, ...)  xproj table: [2 dirs][128 cids][200 gates], bias folded in

__device__ inline float tanh_fast(float x) {
    float e = __expf(2.f * x);
    return 1.f - 2.f / (e + 1.f);
}
__device__ inline float sigmoid_fast(float x) {
    return 1.f / (1.f + __expf(-x));
}

// ---------------- prep: min partials | xproj table | word-embed gather ----------------
// grid 336: [0,256) min partials, [256,272) xproj (dir*8+cidchunk), [272,336) gather

__global__ __launch_bounds__(256) void prep_kernel(
        const float* __restrict__ bert, const float* __restrict__ char_table,
        const float* __restrict__ Wih_f, const float* __restrict__ bih_f, const float* __restrict__ bhh_f,
        const float* __restrict__ Wih_b, const float* __restrict__ bih_b, const float* __restrict__ bhh_b,
        const int* __restrict__ word_ids, const float* __restrict__ word_table,
        float* __restrict__ minp, float* __restrict__ xpt, float* __restrict__ out) {
    int blk = blockIdx.x, tid = threadIdx.x;
    if (blk < 256) {
        const int n = Bb * Ss * Hh;
        float m = FLT_MAX;
        for (int i = blk * 256 + tid; i < n; i += 256 * 256) m = fminf(m, bert[i]);
        #pragma unroll
        for (int off = 32; off; off >>= 1) m = fminf(m, __shfl_down(m, off, 64));
        __shared__ float red[4];
        if ((tid & 63) == 0) red[tid >> 6] = m;
        __syncthreads();
        if (tid == 0) minp[blk] = fminf(fminf(red[0], red[1]), fminf(red[2], red[3]));
    } else if (blk < 272) {
        int idx = blk - 256;            // dir*8 + cid-chunk
        int dir = idx >> 3, c0 = (idx & 7) * 16;
        const float* Wih = dir ? Wih_b : Wih_f;
        const float* bih = dir ? bih_b : bih_f;
        const float* bhh = dir ? bhh_b : bhh_f;
        __shared__ float ct[16][Dc];
        for (int e = tid; e < 16 * Dc; e += 256)
            ((float*)ct)[e] = char_table[c0 * Dc + e];   // contiguous
        __syncthreads();
        if (tid < NG) {
            float w[Dc];
            #pragma unroll
            for (int j = 0; j < Dc; j++) w[j] = Wih[tid * Dc + j];
            float bias = bih[tid] + bhh[tid];
            for (int cid = 0; cid < 16; cid++) {
                float a = bias;
                #pragma unroll
                for (int j = 0; j < Dc; j++) a += w[j] * ct[cid][j];
                xpt[(dir * CV + c0 + cid) * NG + tid] = a;
            }
        }
    } else {
        for (int i = (blk - 272) * 256 + tid; i < Bb * Ll * WD; i += 64 * 256) {
            int bl = i / WD, d = i - bl * WD;
            out[(size_t)bl * OUTC + Hh + d] = word_table[(size_t)word_ids[bl] * WD + d];
        }
    }
}

// ---------------- word_reps masked max, direct to out ----------------
// grid 384 = 6 h-chunks(128) * 32 l-tiles(8 rows) * 2 b
// waves split S 4x96; lane holds float2 of h; masks are block-uniform -> scalar branch

#define LT 8

__global__ __launch_bounds__(256) void word_kernel(
        const float* __restrict__ bert, const int* __restrict__ p2w,
        const float* __restrict__ minp, float* __restrict__ out) {
    int tid = threadIdx.x;
    __shared__ float sminv;
    __shared__ float sacc[4][LT][128];
    if (tid < 64) {
        float m = fminf(fminf(minp[tid], minp[tid + 64]),
                        fminf(minp[tid + 128], minp[tid + 192]));
        #pragma unroll
        for (int off = 32; off; off >>= 1) m = fminf(m, __shfl_down(m, off, 64));
        if (tid == 0) sminv = m;
    }
    int blk = blockIdx.x;
    int hc = blk % 6;            // 6 chunks of 128 h
    int lt = (blk / 6) & 31;     // 32 tiles of 8 l
    int b  = blk / 192;
    int l0 = lt * LT;
    int w    = tid >> 6;         // wave id -> s chunk
    int lane = tid & 63;

    const float2* bb2 = (const float2*)(bert + (size_t)b * Ss * Hh + hc * 128);
    const int*    pm  = p2w + ((size_t)b * Ll + l0) * Ss;

    float2 acc[LT];
    #pragma unroll
    for (int r = 0; r < LT; r++) { acc[r].x = -FLT_MAX; acc[r].y = -FLT_MAX; }

    int s0 = w * 96;
    for (int s = s0; s < s0 + 96; s += 4) {
        float2 v0 = bb2[(size_t)(s + 0) * 384 + lane];
        float2 v1 = bb2[(size_t)(s + 1) * 384 + lane];
        float2 v2 = bb2[(size_t)(s + 2) * 384 + lane];
        float2 v3 = bb2[(size_t)(s + 3) * 384 + lane];
        #pragma unroll
        for (int r = 0; r < LT; r++) {
            const int* pr = pm + r * Ss + s;
            // block-uniform masks -> scalar branches skip inactive s
            if (pr[0]) { acc[r].x = fmaxf(acc[r].x, v0.x); acc[r].y = fmaxf(acc[r].y, v0.y); }
            if (pr[1]) { acc[r].x = fmaxf(acc[r].x, v1.x); acc[r].y = fmaxf(acc[r].y, v1.y); }
            if (pr[2]) { acc[r].x = fmaxf(acc[r].x, v2.x); acc[r].y = fmaxf(acc[r].y, v2.y); }
            if (pr[3]) { acc[r].x = fmaxf(acc[r].x, v3.x); acc[r].y = fmaxf(acc[r].y, v3.y); }
        }
    }
    #pragma unroll
    for (int r = 0; r < LT; r++)
        *(float2*)&sacc[w][r][lane * 2] = acc[r];
    __syncthreads();

    float mv = sminv;
    #pragma unroll
    for (int e = tid; e < LT * 128; e += 256) {
        int r = e >> 7, c = e & 127;
        float m0 = fmaxf(sacc[0][r][c], sacc[1][r][c]);
        float m1 = fmaxf(sacc[2][r][c], sacc[3][r][c]);
        float m  = fmaxf(m0, m1);
        if (m == -FLT_MAX) m = mv;      // fully-masked row -> global min fill
        out[((size_t)(b * Ll + l0 + r)) * OUTC + hc * 128 + c] = m;
    }
}

// ---------------- char bi-LSTM: one block per (chain, dir), xproj from table ----------------

__global__ __launch_bounds__(256) void lstm_kernel(
        const int* __restrict__ char_ids, const int* __restrict__ char_count,
        const float* __restrict__ Whh_f, const float* __restrict__ Whh_b,
        const float* __restrict__ xpt, float* __restrict__ out) {
    int n = blockIdx.x, dir = blockIdx.y, tid = threadIdx.x;
    const float* Whh = dir ? Whh_b : Whh_f;

    __shared__ float xg[Tc][NG];
    __shared__ float gs[NG];
    __shared__ __align__(16) float hs[52];
    __shared__ int scid[Tc];

    int len = char_count[n];
    if (len < 1) len = 1;
    if (tid < Tc) {
        int t = tid;
        int st = dir ? (t < len ? len - 1 - t : t) : t;   // bwd: reverse valid prefix
        scid[t] = char_ids[n * Tc + st];
    }
    if (tid < 52) hs[tid] = 0.f;
    __syncthreads();

    for (int e = tid; e < Tc * NG; e += 256) {
        int t = e / NG, g = e - t * NG;
        xg[t][g] = xpt[(dir * CV + scid[t]) * NG + g];    // coalesced row gather
    }
    float w[52];
    if (tid < NG) {
        #pragma unroll
        for (int j = 0; j < Dc; j++) w[j] = Whh[tid * Dc + j];
        w[50] = 0.f; w[51] = 0.f;
    }
    __syncthreads();

    float c = 0.f, maxv = -FLT_MAX;
    for (int t = 0; t < Tc; t++) {
        if (tid < NG) {
            float g = xg[t][tid];
            #pragma unroll
            for (int j = 0; j < 52; j += 4) {
                float4 hv = *(const float4*)&hs[j];      // broadcast reads
                g += hv.x * w[j] + hv.y * w[j+1] + hv.z * w[j+2] + hv.w * w[j+3];
            }
            gs[tid] = g;
        }
        __syncthreads();
        if (tid < Dc) {
            float si = sigmoid_fast(gs[tid]);
            float sf = sigmoid_fast(gs[tid + 50]);
            float tg = tanh_fast(gs[tid + 100]);
            float so = sigmoid_fast(gs[tid + 150]);
            c = sf * c + si * tg;
            float h = so * tanh_fast(c);
            hs[tid] = h;
            if (t < len) maxv = fmaxf(maxv, h);          // ragged max (scan order == valid region both dirs)
        }
        __syncthreads();
    }
    if (tid < Dc)
        out[(size_t)n * OUTC + (Hh + WD) + dir * Dc + tid] = maxv;
}

extern "C" void kernel_launch(void* const* d_in, const int* in_sizes, int n_in,
                              void* d_out, int out_size, void* d_ws, size_t ws_size,
                              hipStream_t stream) {
    const float* bert       = (const float*)d_in[0];
    const int*   p2w        = (const int*)d_in[1];
    const int*   word_ids   = (const int*)d_in[2];
    const int*   char_count = (const int*)d_in[3];
    const int*   char_ids   = (const int*)d_in[4];
    // d_in[5] token_masks_char: consistent with char_count, unused
    const float* word_table = (const float*)d_in[6];
    const float* char_table = (const float*)d_in[7];
    const float* Wih_f = (const float*)d_in[8];
    const float* Whh_f = (const float*)d_in[9];
    const float* bih_f = (const float*)d_in[10];
    const float* bhh_f = (const float*)d_in[11];
    const float* Wih_b = (const float*)d_in[12];
    const float* Whh_b = (const float*)d_in[13];
    const float* bih_b = (const float*)d_in[14];
    const float* bhh_b = (const float*)d_in[15];
    float* out = (float*)d_out;

    float* minp = (float*)d_ws;          // 256 floats
    float* xpt  = minp + 256;            // 2*128*200 floats (~205 KB)

    prep_kernel<<<336, 256, 0, stream>>>(
        bert, char_table, Wih_f, bih_f, bhh_f, Wih_b, bih_b, bhh_b,
        word_ids, word_table, minp, xpt, out);
    word_kernel<<<384, 256, 0, stream>>>(bert, p2w, minp, out);
    lstm_kernel<<<dim3(512, 2), 256, 0, stream>>>(
        char_ids, char_count, Whh_f, Whh_b, xpt, out);
}